// Round 5
// baseline (376.832 us; speedup 1.0000x reference)
//
#include <hip/hip_runtime.h>

// GQA_22436909154699: softmax over a size-1 axis == 1.0, so the reference
// reduces to  out[bl, g*512+h*64+d] = (x @ Wkv + bkv)[bl, g*128+64+d].
// => one (16384 x 2048) @ (2048 x 256) GEMM (v-cols only) + broadcast x8.
// R5: R4 (uncoupled waves, no barriers, register dbuf) with the WAR bug
// fixed — MFMA consumes the prefetch registers BEFORE they are refilled.

#define EMBED 2048
#define KITERS 64  // k-slabs of 32

typedef _Float16 half8 __attribute__((ext_vector_type(8)));
typedef float f32x4 __attribute__((ext_vector_type(4)));

// ---- pre-pass: Bt[n][k] (f16) = Wkv[k][vcol(n)], vcol(n)=(n>>6)*128+64+(n&63)
__global__ __launch_bounds__(256) void prep_b(const float* __restrict__ Wkv,
                                              _Float16* __restrict__ Bt) {
  const int t = threadIdx.x;
  const int kb = blockIdx.x * 8;  // 256 blocks cover k = 0..2047
  const int vcol = ((t >> 6) * 128) + 64 + (t & 63);
  float v[8];
#pragma unroll
  for (int i = 0; i < 8; ++i) v[i] = Wkv[(size_t)(kb + i) * 512 + vcol];
  half8 h;
#pragma unroll
  for (int i = 0; i < 8; ++i) h[i] = (_Float16)v[i];
  *(half8*)&Bt[(size_t)t * EMBED + kb] = h;
}

__device__ __forceinline__ half8 cvt8(f32x4 lo, f32x4 hi) {
  half8 r;
#pragma unroll
  for (int j = 0; j < 4; ++j) {
    r[j] = (_Float16)lo[j];
    r[4 + j] = (_Float16)hi[j];
  }
  return r;
}

// ---- main: each wave computes V[m0:m0+16, n0:n0+64] and writes its
// broadcast directly (n-range == one GQA group == 512 contiguous out cols).
__global__ __launch_bounds__(256, 4) void gqa_main(
    const float* __restrict__ x, const _Float16* __restrict__ Bt,
    const float* __restrict__ bkv, float* __restrict__ out) {
  __shared__ float Vs[4 * 16 * 68];  // per-wave private 16x68 patch (17.4 KB)

  const int tid = threadIdx.x;
  const int wave = tid >> 6;
  const int lane = tid & 63;
  const int lm = lane & 15;
  const int lq = lane >> 4;

  const int nb = blockIdx.x & 3;   // n-group: cols nb*64..+64 of V
  const int mb = blockIdx.x >> 2;  // 64-row m block
  const int m0 = mb * 64 + wave * 16;

  // A: lane -> x[m0+lm][kt*32 + lq*8 + j] (two f32x4)
  const float* ag = x + (size_t)(m0 + lm) * EMBED + lq * 8;
  // B frag ni: lane -> Bt[nb*64 + ni*16 + lm][kt*32 + lq*8 + j] (one half8)
  const _Float16* bg = Bt + (size_t)(nb * 64 + lm) * EMBED + lq * 8;

  f32x4 acc[4] = {};
  f32x4 aA[2], aB[2];
  half8 bA[4], bB[4];

#define LOADA(kt, R)                              \
  {                                               \
    const float* p_ = ag + (kt) * 32;             \
    R[0] = *(const f32x4*)p_;                     \
    R[1] = *(const f32x4*)(p_ + 4);               \
  }
#define LOADB(kt, R)                                                        \
  {                                                                         \
    const _Float16* p_ = bg + (kt) * 32;                                    \
    _Pragma("unroll") for (int ni_ = 0; ni_ < 4; ++ni_)                     \
        R[ni_] = *(const half8*)(p_ + (size_t)ni_ * 16 * EMBED);            \
  }
#define MFMA4(af, R)                                                          \
  {                                                                          \
    _Pragma("unroll") for (int ni_ = 0; ni_ < 4; ++ni_)                      \
        acc[ni_] = __builtin_amdgcn_mfma_f32_16x16x32_f16(af, R[ni_],        \
                                                          acc[ni_], 0, 0, 0); \
  }

  LOADA(0, aA);
  LOADB(0, bA);
  LOADA(1, aB);
  LOADB(1, bB);

  for (int kt = 0; kt < KITERS; kt += 2) {
    {  // even slab: consume set A FIRST, then refill for kt+2
      half8 af = cvt8(aA[0], aA[1]);
      MFMA4(af, bA);
      if (kt + 2 < KITERS) {
        LOADA(kt + 2, aA);
        LOADB(kt + 2, bA);
      }
    }
    {  // odd slab: consume set B FIRST, then refill for kt+3
      half8 af = cvt8(aB[0], aB[1]);
      MFMA4(af, bB);
      if (kt + 3 < KITERS) {
        LOADA(kt + 3, aB);
        LOADB(kt + 3, bB);
      }
    }
  }

  // ---- epilogue (wave-private, barrier-free) ----
  // C/D layout: col(n-within-tile) = lm, row(m) = lq*4 + r.
  float* vw = Vs + wave * (16 * 68);
#pragma unroll
  for (int ni = 0; ni < 4; ++ni) {
    const float bias = bkv[nb * 128 + 64 + ni * 16 + lm];
#pragma unroll
    for (int r = 0; r < 4; ++r) {
      vw[(lq * 4 + r) * 68 + ni * 16 + lm] = acc[ni][r] + bias;
    }
  }
  asm volatile("s_waitcnt lgkmcnt(0)" ::: "memory");  // same-wave DS ordering

  // broadcast write: out[m0+row][nb*512 + c4*4 .. +3] = V[row][(c4&15)*4 ..]
  f32x4* out4 = (f32x4*)(out + (size_t)m0 * EMBED + nb * 512);
#pragma unroll 8
  for (int i = 0; i < 32; ++i) {
    const int f = i * 64 + lane;  // 0..2047 over 16 rows x 128 float4
    const int row = f >> 7;
    const int c4 = f & 127;
    const int d4 = c4 & 15;
    out4[(size_t)row * 512 + c4] = *(const f32x4*)&vw[row * 68 + d4 * 4];
  }
}

extern "C" void kernel_launch(void* const* d_in, const int* in_sizes, int n_in,
                              void* d_out, int out_size, void* d_ws, size_t ws_size,
                              hipStream_t stream) {
  const float* x = (const float*)d_in[0];
  // d_in[1] = Wq, d_in[2] = bq : dead code (softmax over size-1 axis == 1)
  const float* Wkv = (const float*)d_in[3];
  const float* bkv = (const float*)d_in[4];
  float* out = (float*)d_out;
  _Float16* Bt = (_Float16*)d_ws;  // 256*2048 f16 = 1 MB scratch

  prep_b<<<256, 256, 0, stream>>>(Wkv, Bt);
  gqa_main<<<256 * 4, 256, 0, stream>>>(x, Bt, bkv, out);
}

// Round 6
// 281.181 us; speedup vs baseline: 1.3402x; 1.3402x over previous
//
#include <hip/hip_runtime.h>

// GQA_22436909154699: softmax over a size-1 axis == 1.0, so the reference
// reduces to  out[bl, g*512+h*64+d] = (x @ Wkv + bkv)[bl, g*128+64+d].
// => one (16384 x 2048) @ (2048 x 256) GEMM (v-cols only) + broadcast x8.
// R6: m97-style 64x64x64 tile, 4 blocks/CU, single LDS buffer with
// lgkmcnt-ONLY barriers (global prefetch stays in flight across s_barrier),
// coalesced staging, padded LDS (<=2-way), XCD swizzle for x L2 reuse.

#define EMBED 2048
#define BK 64
#define KIT (EMBED / BK)  // 32
#define SA 72             // A/B LDS row stride in halfs (144 B)
#define SV 68             // epilogue V stride in floats

typedef _Float16 half8 __attribute__((ext_vector_type(8)));
typedef _Float16 half4v __attribute__((ext_vector_type(4)));
typedef float f32x4 __attribute__((ext_vector_type(4)));

// lgkm-only barrier: LDS ordering enforced, global loads stay in flight.
#define BAR() asm volatile("s_waitcnt lgkmcnt(0)\ns_barrier" ::: "memory")

// ---- pre-pass: Bt[n][k] (f16) = Wkv[k][vcol(n)], vcol(n)=(n>>6)*128+64+(n&63)
__global__ __launch_bounds__(256) void prep_b(const float* __restrict__ Wkv,
                                              _Float16* __restrict__ Bt) {
  const int t = threadIdx.x;
  const int kb = blockIdx.x * 8;  // 256 blocks cover k = 0..2047
  const int vcol = ((t >> 6) * 128) + 64 + (t & 63);
  float v[8];
#pragma unroll
  for (int i = 0; i < 8; ++i) v[i] = Wkv[(size_t)(kb + i) * 512 + vcol];
  half8 h;
#pragma unroll
  for (int i = 0; i < 8; ++i) h[i] = (_Float16)v[i];
  *(half8*)&Bt[(size_t)t * EMBED + kb] = h;
}

// ---- main: block = 64m x 64n tile, K-loop over 32 slabs of 64.
__global__ __launch_bounds__(256, 4) void gqa_main(
    const float* __restrict__ x, const _Float16* __restrict__ Bt,
    const float* __restrict__ bkv, float* __restrict__ out) {
  __shared__ __align__(16) char smem[2 * 64 * SA * 2];  // 18432 B
  _Float16* As = (_Float16*)smem;       // 64 x SA halfs
  _Float16* Bs = As + 64 * SA;          // 64 x SA halfs
  float* Vs = (float*)smem;             // overlay: 64 x SV fp32 = 17408 B

  const int tid = threadIdx.x;
  const int wave = tid >> 6;
  const int lane = tid & 63;
  const int lm = lane & 15;
  const int lq = lane >> 4;
  // XCD swizzle: 4 n-group blocks of one mb land on the same XCD (i%8).
  const int bi = blockIdx.x;
  const int nb = (bi >> 3) & 3;
  const int mb = ((bi >> 5) << 3) | (bi & 7);
  const int mi2 = wave & 1;   // wave's m-half (32 rows)
  const int ni2 = wave >> 1;  // wave's n-half (32 cols)

  // staging: A = 64 rows x 64 fp32 (coalesced 256B/row), chunks +16 rows
  const int ar = tid >> 4, ac = (tid & 15) * 4;
  const float* ap = x + (size_t)(mb * 64 + ar) * EMBED + ac;
  _Float16* aw = As + ar * SA + ac;
  // staging: B = 64 rows x 64 f16, thread: row t>>2, cols (t&3)*8 and +32
  const int br = tid >> 2, bc = (tid & 3) * 8;
  const _Float16* bp = Bt + (size_t)(nb * 64 + br) * EMBED + bc;
  _Float16* bw = Bs + br * SA + bc;

  // fragment read bases: row = half*32 + mi/ni*16 + lm, k = ks*32 + lq*8
  const _Float16* ard = As + (mi2 * 32 + lm) * SA + lq * 8;
  const _Float16* brd = Bs + (ni2 * 32 + lm) * SA + lq * 8;

  f32x4 pa[4];
  half8 pb[2];

#define LOADAB(kt)                                                   \
  {                                                                  \
    const float* p_ = ap + (kt) * BK;                                \
    pa[0] = *(const f32x4*)p_;                                       \
    pa[1] = *(const f32x4*)(p_ + 16 * EMBED);                        \
    pa[2] = *(const f32x4*)(p_ + 32 * EMBED);                        \
    pa[3] = *(const f32x4*)(p_ + 48 * EMBED);                        \
    const _Float16* q_ = bp + (kt) * BK;                             \
    pb[0] = *(const half8*)q_;                                       \
    pb[1] = *(const half8*)(q_ + 32);                                \
  }

  f32x4 acc[2][2] = {};

  LOADAB(0);
  for (int kt = 0; kt < KIT; ++kt) {
    // stage (fine-grained vmcnt waits happen here, one compute-phase late)
#pragma unroll
    for (int c = 0; c < 4; ++c) {
      half4v h;
#pragma unroll
      for (int j = 0; j < 4; ++j) h[j] = (_Float16)pa[c][j];
      *(half4v*)(aw + c * 16 * SA) = h;
    }
    *(half8*)bw = pb[0];
    *(half8*)(bw + 32) = pb[1];
    BAR();  // tiles visible; prefetch (below) will fly across compute

    if (kt + 1 < KIT) LOADAB(kt + 1);

    half8 af[2][2], bf[2][2];
#pragma unroll
    for (int mi = 0; mi < 2; ++mi)
#pragma unroll
      for (int ks = 0; ks < 2; ++ks)
        af[mi][ks] = *(const half8*)(ard + mi * 16 * SA + ks * 32);
#pragma unroll
    for (int ni = 0; ni < 2; ++ni)
#pragma unroll
      for (int ks = 0; ks < 2; ++ks)
        bf[ni][ks] = *(const half8*)(brd + ni * 16 * SA + ks * 32);
#pragma unroll
    for (int mi = 0; mi < 2; ++mi)
#pragma unroll
      for (int ni = 0; ni < 2; ++ni)
#pragma unroll
        for (int ks = 0; ks < 2; ++ks)
          acc[mi][ni] = __builtin_amdgcn_mfma_f32_16x16x32_f16(
              af[mi][ks], bf[ni][ks], acc[mi][ni], 0, 0, 0);
    BAR();  // ds_reads done block-wide; next stores may proceed
  }

  // epilogue: bias + V(64x64) to LDS (C/D: col = lm, row = lq*4 + r)
#pragma unroll
  for (int ni = 0; ni < 2; ++ni) {
    const int nc = ni2 * 32 + ni * 16 + lm;
    const float bias = bkv[nb * 128 + 64 + nc];
#pragma unroll
    for (int mi = 0; mi < 2; ++mi) {
      f32x4 v = acc[mi][ni];
#pragma unroll
      for (int r = 0; r < 4; ++r) {
        Vs[(mi2 * 32 + mi * 16 + lq * 4 + r) * SV + nc] = v[r] + bias;
      }
    }
  }
  BAR();

  // broadcast: block writes out[mb*64 .. +64][nb*512 .. +512], coalesced
  f32x4* out4 = (f32x4*)(out + (size_t)(mb * 64) * EMBED + nb * 512);
#pragma unroll 8
  for (int i = 0; i < 32; ++i) {
    const int f = i * 256 + tid;  // 0..8191 over 64 rows x 128 float4
    const int row = f >> 7;
    const int c4 = f & 127;
    const int d4 = c4 & 15;
    out4[(size_t)row * 512 + c4] = *(const f32x4*)&Vs[row * SV + d4 * 4];
  }
}

extern "C" void kernel_launch(void* const* d_in, const int* in_sizes, int n_in,
                              void* d_out, int out_size, void* d_ws, size_t ws_size,
                              hipStream_t stream) {
  const float* x = (const float*)d_in[0];
  // d_in[1] = Wq, d_in[2] = bq : dead code (softmax over size-1 axis == 1)
  const float* Wkv = (const float*)d_in[3];
  const float* bkv = (const float*)d_in[4];
  float* out = (float*)d_out;
  _Float16* Bt = (_Float16*)d_ws;  // 256*2048 f16 = 1 MB scratch

  prep_b<<<256, 256, 0, stream>>>(Wkv, Bt);
  gqa_main<<<1024, 256, 0, stream>>>(x, Bt, bkv, out);
}

// Round 7
// 279.184 us; speedup vs baseline: 1.3498x; 1.0072x over previous
//
#include <hip/hip_runtime.h>

// GQA_22436909154699: softmax over a size-1 axis == 1.0, so the reference
// reduces to  out[bl, g*512+h*64+d] = (x @ Wkv + bkv)[bl, g*128+64+d].
// => one (16384 x 2048) @ (2048 x 256) GEMM (v-cols only) + broadcast x8.
// R7 = R6 + depth-2 register prefetch (unroll-2, named sets): slab kt's
// global loads are issued ~2 compute phases before their LDS store, so the
// vmcnt wait at the store phase exposes ~300 instead of ~600 cycles.

#define EMBED 2048
#define BK 64
#define KIT (EMBED / BK)  // 32
#define SA 72             // A/B LDS row stride in halfs (144 B, 16B-aligned)
#define SV 68             // epilogue V stride in floats

typedef _Float16 half8 __attribute__((ext_vector_type(8)));
typedef _Float16 half4v __attribute__((ext_vector_type(4)));
typedef float f32x4 __attribute__((ext_vector_type(4)));

// lgkm-only barrier: LDS ordering enforced, global loads stay in flight.
#define BAR() asm volatile("s_waitcnt lgkmcnt(0)\ns_barrier" ::: "memory")

// ---- pre-pass: Bt[n][k] (f16) = Wkv[k][vcol(n)], vcol(n)=(n>>6)*128+64+(n&63)
__global__ __launch_bounds__(256) void prep_b(const float* __restrict__ Wkv,
                                              _Float16* __restrict__ Bt) {
  const int t = threadIdx.x;
  const int kb = blockIdx.x * 4;  // 512 blocks cover k = 0..2047
  const int vcol = ((t >> 6) * 128) + 64 + (t & 63);
  float v[4];
#pragma unroll
  for (int i = 0; i < 4; ++i) v[i] = Wkv[(size_t)(kb + i) * 512 + vcol];
  half4v h;
#pragma unroll
  for (int i = 0; i < 4; ++i) h[i] = (_Float16)v[i];
  *(half4v*)&Bt[(size_t)t * EMBED + kb] = h;
}

// ---- main: block = 64m x 64n tile, K-loop over 32 slabs of 64.
__global__ __launch_bounds__(256, 4) void gqa_main(
    const float* __restrict__ x, const _Float16* __restrict__ Bt,
    const float* __restrict__ bkv, float* __restrict__ out) {
  __shared__ __align__(16) char smem[2 * 64 * SA * 2];  // 18432 B
  _Float16* As = (_Float16*)smem;  // 64 x SA halfs
  _Float16* Bs = As + 64 * SA;     // 64 x SA halfs
  float* Vs = (float*)smem;        // overlay: 64 x SV fp32 = 17408 B

  const int tid = threadIdx.x;
  const int wave = tid >> 6;
  const int lane = tid & 63;
  const int lm = lane & 15;
  const int lq = lane >> 4;
  // XCD swizzle: the 4 n-group blocks of one mb land on the same XCD (i%8).
  const int bi = blockIdx.x;
  const int nb = (bi >> 3) & 3;
  const int mb = ((bi >> 5) << 3) | (bi & 7);
  const int mi2 = wave & 1;   // wave's m-half (32 rows)
  const int ni2 = wave >> 1;  // wave's n-half (32 cols)

  // staging: A = 64 rows x 64 fp32 (coalesced 256B per 16-lane row group)
  const int ar = tid >> 4, ac = (tid & 15) * 4;
  const float* ap = x + (size_t)(mb * 64 + ar) * EMBED + ac;
  _Float16* aw = As + ar * SA + ac;
  // staging: B = 64 rows x 64 f16, thread: row t>>2, cols (t&3)*8 and +32
  const int br = tid >> 2, bc = (tid & 3) * 8;
  const _Float16* bp = Bt + (size_t)(nb * 64 + br) * EMBED + bc;
  _Float16* bw = Bs + br * SA + bc;

  // fragment read bases: row = half*32 + mi/ni*16 + lm, k = ks*32 + lq*8
  const _Float16* ard = As + (mi2 * 32 + lm) * SA + lq * 8;
  const _Float16* brd = Bs + (ni2 * 32 + lm) * SA + lq * 8;

  // two named prefetch sets (depth 2) — never runtime-indexed
  f32x4 pa0[4], pa1[4];
  half8 pb0[2], pb1[2];

#define LOADAB(kt, PA, PB)                       \
  {                                              \
    const float* p_ = ap + (kt) * BK;            \
    PA[0] = *(const f32x4*)p_;                   \
    PA[1] = *(const f32x4*)(p_ + 16 * EMBED);    \
    PA[2] = *(const f32x4*)(p_ + 32 * EMBED);    \
    PA[3] = *(const f32x4*)(p_ + 48 * EMBED);    \
    const _Float16* q_ = bp + (kt) * BK;         \
    PB[0] = *(const half8*)q_;                   \
    PB[1] = *(const half8*)(q_ + 32);            \
  }
#define STAGE(PA, PB)                            \
  {                                              \
    _Pragma("unroll") for (int c_ = 0; c_ < 4; ++c_) { \
      half4v h_;                                 \
      _Pragma("unroll") for (int j_ = 0; j_ < 4; ++j_) \
          h_[j_] = (_Float16)PA[c_][j_];         \
      *(half4v*)(aw + c_ * 16 * SA) = h_;        \
    }                                            \
    *(half8*)bw = PB[0];                         \
    *(half8*)(bw + 32) = PB[1];                  \
  }
#define COMPUTE()                                                         \
  {                                                                       \
    half8 af_[2][2], bf_[2][2];                                           \
    _Pragma("unroll") for (int mi_ = 0; mi_ < 2; ++mi_)                   \
        _Pragma("unroll") for (int ks_ = 0; ks_ < 2; ++ks_)               \
            af_[mi_][ks_] = *(const half8*)(ard + mi_ * 16 * SA + ks_ * 32); \
    _Pragma("unroll") for (int ni_ = 0; ni_ < 2; ++ni_)                   \
        _Pragma("unroll") for (int ks_ = 0; ks_ < 2; ++ks_)               \
            bf_[ni_][ks_] = *(const half8*)(brd + ni_ * 16 * SA + ks_ * 32); \
    _Pragma("unroll") for (int mi_ = 0; mi_ < 2; ++mi_)                   \
        _Pragma("unroll") for (int ni_ = 0; ni_ < 2; ++ni_)               \
            _Pragma("unroll") for (int ks_ = 0; ks_ < 2; ++ks_)           \
                acc[mi_][ni_] = __builtin_amdgcn_mfma_f32_16x16x32_f16(   \
                    af_[mi_][ks_], bf_[ni_][ks_], acc[mi_][ni_], 0, 0, 0); \
  }

  f32x4 acc[2][2] = {};

  LOADAB(0, pa0, pb0);
  LOADAB(1, pa1, pb1);

  for (int kt = 0; kt < KIT; kt += 2) {
    // ---- even phase: slab kt from set 0
    STAGE(pa0, pb0);  // waits vmcnt for set-0 loads (issued 2 phases ago)
    BAR();
    if (kt + 2 < KIT) LOADAB(kt + 2, pa0, pb0);  // refill AFTER consume
    COMPUTE();
    BAR();
    // ---- odd phase: slab kt+1 from set 1
    STAGE(pa1, pb1);
    BAR();
    if (kt + 3 < KIT) LOADAB(kt + 3, pa1, pb1);
    COMPUTE();
    BAR();
  }

  // epilogue: bias + V(64x64) to LDS (C/D: col = lm, row = lq*4 + r)
#pragma unroll
  for (int ni = 0; ni < 2; ++ni) {
    const int nc = ni2 * 32 + ni * 16 + lm;
    const float bias = bkv[nb * 128 + 64 + nc];
#pragma unroll
    for (int mi = 0; mi < 2; ++mi) {
      f32x4 v = acc[mi][ni];
#pragma unroll
      for (int r = 0; r < 4; ++r) {
        Vs[(mi2 * 32 + mi * 16 + lq * 4 + r) * SV + nc] = v[r] + bias;
      }
    }
  }
  BAR();

  // broadcast: block writes out[mb*64 .. +64][nb*512 .. +512], coalesced
  f32x4* out4 = (f32x4*)(out + (size_t)(mb * 64) * EMBED + nb * 512);
#pragma unroll 8
  for (int i = 0; i < 32; ++i) {
    const int f = i * 256 + tid;  // 0..8191 over 64 rows x 128 float4
    const int row = f >> 7;
    const int c4 = f & 127;
    const int d4 = c4 & 15;
    out4[(size_t)row * 512 + c4] = *(const f32x4*)&Vs[row * SV + d4 * 4];
  }
}

extern "C" void kernel_launch(void* const* d_in, const int* in_sizes, int n_in,
                              void* d_out, int out_size, void* d_ws, size_t ws_size,
                              hipStream_t stream) {
  const float* x = (const float*)d_in[0];
  // d_in[1] = Wq, d_in[2] = bq : dead code (softmax over size-1 axis == 1)
  const float* Wkv = (const float*)d_in[3];
  const float* bkv = (const float*)d_in[4];
  float* out = (float*)d_out;
  _Float16* Bt = (_Float16*)d_ws;  // 256*2048 f16 = 1 MB scratch

  prep_b<<<512, 256, 0, stream>>>(Wkv, Bt);
  gqa_main<<<1024, 256, 0, stream>>>(x, Bt, bkv, out);
}